// Round 13
// baseline (223.760 us; speedup 1.0000x reference)
//
#include <hip/hip_runtime.h>
#include <math.h>

namespace {
constexpr int HOP_    = 256;
constexpr int FRAMES_ = 1024;
constexpr int BATCH_  = 16;
constexpr int BINS_   = 513;
constexpr int OUTLEN_ = 262912;              // (1024-1)*256 + 1024
constexpr int FPB_    = 16;                  // frames owned per block
constexpr int BPB_    = FRAMES_ / FPB_;      // 64 blocks per batch
constexpr int OWN_    = FPB_ * HOP_;         // 4096 owned samples
constexpr int BUF_    = OWN_ + 768;          // 4864 (last block span)
constexpr int FB2_    = 576;                 // float2/wave: 512 + 64 skew
}

__device__ __forceinline__ void cmul(float& xr, float& xi, float yr, float yi) {
    float tr = xr * yr - xi * yi;
    xi = xr * yi + xi * yr;
    xr = tr;
}

// out[r] = sum_j in[j] * e^{+2pi i r j / 8}   (hardware-validated block)
__device__ __forceinline__ void dft8(float (&Yr)[8], float (&Yi)[8]) {
    const float t0r = Yr[0] + Yr[4], t0i = Yi[0] + Yi[4];
    const float t1r = Yr[0] - Yr[4], t1i = Yi[0] - Yi[4];
    const float t2r = Yr[2] + Yr[6], t2i = Yi[2] + Yi[6];
    const float t3r = Yr[2] - Yr[6], t3i = Yi[2] - Yi[6];
    const float E0r = t0r + t2r, E0i = t0i + t2i;
    const float E1r = t1r - t3i, E1i = t1i + t3r;
    const float E2r = t0r - t2r, E2i = t0i - t2i;
    const float E3r = t1r + t3i, E3i = t1i - t3r;
    const float u0r = Yr[1] + Yr[5], u0i = Yi[1] + Yi[5];
    const float u1r = Yr[1] - Yr[5], u1i = Yi[1] - Yi[5];
    const float u2r = Yr[3] + Yr[7], u2i = Yi[3] + Yi[7];
    const float u3r = Yr[3] - Yr[7], u3i = Yi[3] - Yi[7];
    const float O0r = u0r + u2r, O0i = u0i + u2i;
    const float O1r = u1r - u3i, O1i = u1i + u3r;
    const float O2r = u0r - u2r, O2i = u0i - u2i;
    const float O3r = u1r + u3i, O3i = u1i - u3r;
    const float rc = 0.7071067811865476f;
    const float W1r = rc * (O1r - O1i), W1i = rc * (O1r + O1i);
    const float W2r = -O2i,             W2i = O2r;
    const float W3r = -rc * (O3r + O3i), W3i = rc * (O3r - O3i);
    Yr[0] = E0r + O0r; Yi[0] = E0i + O0i;
    Yr[4] = E0r - O0r; Yi[4] = E0i - O0i;
    Yr[1] = E1r + W1r; Yi[1] = E1i + W1i;
    Yr[5] = E1r - W1r; Yi[5] = E1i - W1i;
    Yr[2] = E2r + W2r; Yi[2] = E2i + W2i;
    Yr[6] = E2r - W2r; Yi[6] = E2i - W2i;
    Yr[3] = E3r + W3r; Yi[3] = E3i + W3i;
    Yr[7] = E3r - W3r; Yi[7] = E3i - W3i;
}

// One wave = one 512-pt radix-8^3 FFT. float2-packed per-wave stage buffers
// (exact 4-way banks = b64 floor). Accumulation via LDS ds_add_f32 atomics:
// no step barriers (2 barriers total). Next-frame global loads issued
// between stage-1 and stage-2 to hide HBM/L2 latency under DS+VALU work.
__global__ __launch_bounds__(256, 4)
void istft_r8v2_kernel(const float* __restrict__ sre,
                       const float* __restrict__ sim,
                       float* __restrict__ out)
{
    __shared__ float2 fbuf[4][FB2_];
    __shared__ __align__(16) float acc[BUF_];

    const int tid   = threadIdx.x;
    const int l     = tid & 63;
    const int wv    = tid >> 6;
    const int blkid = blockIdx.x;
    const int b     = blockIdx.y;
    const int F0    = blkid * FPB_;
    const int blen  = (blkid == BPB_ - 1) ? BUF_ : OWN_;

    float2* fb = fbuf[wv];

    // zero acc (float4 stores)
    {
        float4* a4 = reinterpret_cast<float4*>(acc);
        for (int v = tid; v < BUF_ / 4; v += 256)
            a4[v] = make_float4(0.f, 0.f, 0.f, 0.f);
    }

    // ---- per-lane constants (verified on HW, rounds 3/8) ----
    float Wkr[8], Wki[8];           // e^{2pi i (l+64r)/1024}
    {
        float s, c; sincosf(0.006135923151542565f * (float)l, &s, &c);
        Wkr[0] = c; Wki[0] = s;
        const float pr = 0.9238795325112867f, pq = 0.3826834323650898f;
        #pragma unroll
        for (int r = 1; r < 8; ++r) {
            Wkr[r] = Wkr[r-1]; Wki[r] = Wki[r-1];
            cmul(Wkr[r], Wki[r], pr, pq);
        }
    }
    float T1r[8], T1i[8];           // (w512^l)^r
    {
        T1r[0] = 1.f; T1i[0] = 0.f;
        float br = Wkr[0], bi = Wki[0];
        cmul(br, bi, Wkr[0], Wki[0]);
        T1r[1] = br; T1i[1] = bi;
        #pragma unroll
        for (int r = 2; r < 8; ++r) {
            T1r[r] = T1r[r-1]; T1i[r] = T1i[r-1];
            cmul(T1r[r], T1i[r], br, bi);
        }
    }
    float T2r[8], T2i[8];           // (w64^(l&7))^s
    {
        float s, c; sincosf(0.09817477042468103f * (float)(l & 7), &s, &c);
        T2r[0] = 1.f; T2i[0] = 0.f;
        T2r[1] = c;   T2i[1] = s;
        #pragma unroll
        for (int k = 2; k < 8; ++k) {
            T2r[k] = T2r[k-1]; T2i[k] = T2i[k-1];
            cmul(T2r[k], T2i[k], c, s);
        }
    }
    const int c_ = ((l & 7) << 3) + (l >> 3);
    float we[8], wo[8];             // hann(2n), hann(2n+1), n = 64w + c_
    {
        float sf, cf; sincosf(0.012271846303085130f * (float)c_, &sf, &cf);
        const float C2 = 0.9999811752826011f, S2 = 0.006135884649154475f;
        const float rc = 0.7071067811865476f;
        const float cw[8] = {1.f, rc, 0.f, -rc, -1.f, -rc, 0.f, rc};
        const float sw[8] = {0.f, rc, 1.f, rc, 0.f, -rc, -1.f, -rc};
        #pragma unroll
        for (int w = 0; w < 8; ++w) {
            const float ct = cw[w] * cf - sw[w] * sf;
            const float st = sw[w] * cf + cw[w] * sf;
            we[w] = 0.5f - 0.5f * ct;
            wo[w] = 0.5f - 0.5f * (ct * C2 - st * S2);
        }
    }

    __syncthreads();   // acc zero visible; last barrier until write-out

    const float cs = 1.0f / 1024.0f;
    const int sk1f = l + (l >> 3);            // stage-1 write base (float2)
    const int sk2f = 72 * (l >> 3) + (l & 7); // stage-2 base
    const int sk3f = 9 * l;                   // stage-3 base
    const int lo_fi = (blkid == 0) ? 0 : -3;

    float La[8], Lb[8], Lc[8], Ld[8];  // sre[k], sim[k], sre[512-k], sim[512-k]

    auto issue = [&](int fi) {
        const int f = F0 + fi;
        const size_t base = ((size_t)b * FRAMES_ + f) * BINS_;
        #pragma unroll
        for (int r = 0; r < 8; ++r) {
            const int k = l + 64 * r;
            La[r] = sre[base + k];
            Lb[r] = sim[base + k];
            Lc[r] = sre[base + 512 - k];
            Ld[r] = sim[base + 512 - k];
        }
    };

    // wave wv handles frames fi = wv - 3 + 4t, t = 0..4 (atomic acc -> no
    // cross-wave spacing constraint). Prefetch t+1's loads under t's stages.
    {
        const int fi0 = wv - 3;
        if (fi0 >= lo_fi) issue(fi0);
    }

    #pragma unroll 1
    for (int t = 0; t < 5; ++t) {
        const int fi  = wv - 3 + 4 * t;
        const bool val   = (fi >= lo_fi) && (fi <= 15);
        const int  fin   = fi + 4;
        const bool vnext = (t < 4) && (fin >= lo_fi) && (fin <= 15);

        float Yr[8], Yi[8];
        if (val) {
            // ---- z-prep from prefetched regs (scale 1/1024)
            #pragma unroll
            for (int r = 0; r < 8; ++r) {
                float ar = La[r], ai = Lb[r];
                float br = Lc[r], bi = -Ld[r];
                if (r == 0 && l == 0) { ai = 0.f; bi = 0.f; }
                const float er = (ar + br) * cs, ei = (ai + bi) * cs;
                const float dr = (ar - br) * cs, di = (ai - bi) * cs;
                const float orr = Wkr[r] * dr - Wki[r] * di;
                const float oii = Wkr[r] * di + Wki[r] * dr;
                Yr[r] = er - oii;
                Yi[r] = ei + orr;
            }
            // ---- stage 1 (registers) -> float2 LDS at sk1f + 72m
            dft8(Yr, Yi);
            #pragma unroll
            for (int r = 1; r < 8; ++r) cmul(Yr[r], Yi[r], T1r[r], T1i[r]);
            #pragma unroll
            for (int r = 0; r < 8; ++r)
                fb[sk1f + 72 * r] = make_float2(Yr[r], Yi[r]);
        }

        if (vnext) issue(fin);   // global loads overlap stages 2-3 + atomics

        if (val) {
            // ---- stage 2: float2 at sk2f + 9v, in-place
            #pragma unroll
            for (int v = 0; v < 8; ++v) {
                const float2 p = fb[sk2f + 9 * v];
                Yr[v] = p.x; Yi[v] = p.y;
            }
            dft8(Yr, Yi);
            #pragma unroll
            for (int s = 1; s < 8; ++s) cmul(Yr[s], Yi[s], T2r[s], T2i[s]);
            #pragma unroll
            for (int s = 0; s < 8; ++s)
                fb[sk2f + 9 * s] = make_float2(Yr[s], Yi[s]);

            // ---- stage 3: float2 at sk3f + j
            #pragma unroll
            for (int j = 0; j < 8; ++j) {
                const float2 p = fb[sk3f + j];
                Yr[j] = p.x; Yi[j] = p.y;
            }
            dft8(Yr, Yi);
            // lane holds z[n], n = 64w + c_ -> x[2n]=Re, x[2n+1]=Im

            // ---- window + LDS float atomics (fire-and-forget ds_add_f32)
            const int p0 = fi * HOP_ + 2 * c_;
            #pragma unroll
            for (int w = 0; w < 8; ++w) {
                const int pos = p0 + 128 * w;
                if ((unsigned)pos < (unsigned)blen) {
                    atomicAdd(&acc[pos],     Yr[w] * we[w]);
                    atomicAdd(&acc[pos + 1], Yi[w] * wo[w]);
                }
            }
        }
    }

    __syncthreads();

    // ---- exclusive write-out of owned span (stride-1, float4)
    const size_t ob = (size_t)b * OUTLEN_ + (size_t)F0 * HOP_;
    float4* o4 = reinterpret_cast<float4*>(out + ob);
    const float4* a4 = reinterpret_cast<const float4*>(acc);
    for (int v = tid; v < (blen >> 2); v += 256) o4[v] = a4[v];
}

extern "C" void kernel_launch(void* const* d_in, const int* in_sizes, int n_in,
                              void* d_out, int out_size, void* d_ws, size_t ws_size,
                              hipStream_t stream)
{
    (void)in_sizes; (void)n_in; (void)d_ws; (void)ws_size; (void)out_size;
    const float* sre = (const float*)d_in[0];
    const float* sim = (const float*)d_in[1];
    float* out = (float*)d_out;

    istft_r8v2_kernel<<<dim3(BPB_, BATCH_), dim3(256), 0, stream>>>(sre, sim, out);
}